// Round 2
// baseline (267.612 us; speedup 1.0000x reference)
//
#include <hip/hip_runtime.h>

// Triplane sampling, MI355X.
// Reference reduces to: for each point (x,y,z), sample 3 planes at
//   p0: (gx,gy)=(y,x)   p1: (gx,gy)=(z,x)   p2: (gx,gy)=(y,z)
// bilinear, align_corners=True, zero-pad OOB (only reachable at upper edge
// with zero weight). Output out[m*32+c] = sum over planes.

#define RRTP 262144   // 512*512
#define CTP  32

typedef float f32x4 __attribute__((ext_vector_type(4)));

// ---------------- Kernel 1: [3][C][R][R] -> [3][R][R][C] transpose ----------
__global__ __launch_bounds__(256) void tp_transpose(const float* __restrict__ in,
                                                    float* __restrict__ out,
                                                    const int* __restrict__ oid) {
    __shared__ float tile[256][33];            // +1 pad: conflict-free both phases
    const int b     = blockIdx.x;              // 0..3071
    const int plane = b >> 10;                 // /1024
    const int rr0   = (b & 1023) << 8;         // *256
    const int t     = threadIdx.x;

    const float* src = in + (size_t)oid[0] * (3u * CTP * RRTP)
                          + (size_t)plane * (CTP * RRTP) + rr0 + t;
    #pragma unroll
    for (int c = 0; c < 32; ++c)               // coalesced 256B/wave reads
        tile[t][c] = src[(size_t)c * RRTP];
    __syncthreads();

    float* dst = out + (size_t)plane * ((size_t)RRTP * CTP) + (size_t)rr0 * CTP;
    const int w = t >> 5, c2 = t & 31;
    #pragma unroll
    for (int k = 0; k < 32; ++k) {             // coalesced 1KB/block stores
        const int r = (k << 3) + w;            // row in tile
        dst[(size_t)(k << 8) + t] = tile[r][c2];   // == dst[r*32 + c2]
    }
}

// ---------------- Kernel 2: sample from channel-last layout -----------------
// One thread per (point, channel-quad): tid -> m = tid>>3, q = (tid&7)*4.
// Each corner load is a float4; 8 lanes of the same point cover a contiguous
// 128B channel row -> fully-utilized cache lines.
__global__ __launch_bounds__(256) void tp_sample(const float* __restrict__ xyz,
                                                 const float* __restrict__ tp,
                                                 float* __restrict__ out,
                                                 int Mtot) {
    const int tid = blockIdx.x * 256 + threadIdx.x;
    const int m = tid >> 3;
    if (m >= Mtot) return;
    const int q = (tid & 7) << 2;

    const float px = xyz[m * 3 + 0];
    const float py = xyz[m * 3 + 1];
    const float pz = xyz[m * 3 + 2];

    const float gxs[3] = {py, pz, py};
    const float gys[3] = {px, px, pz};

    f32x4 acc = {0.f, 0.f, 0.f, 0.f};

    #pragma unroll
    for (int p = 0; p < 3; ++p) {
        const float xf = (gxs[p] + 1.0f) * (0.5f * 511.0f);
        const float yf = (gys[p] + 1.0f) * (0.5f * 511.0f);
        const float x0f = floorf(xf), y0f = floorf(yf);
        float wx1 = xf - x0f, wy1 = yf - y0f;
        float wx0 = 1.0f - wx1, wy0 = 1.0f - wy1;

        int x0 = (int)x0f, y0 = (int)y0f;
        int x1 = x0 + 1,   y1 = y0 + 1;
        // zero-pad semantics: only the upper edge is reachable; weight is
        // already 0 there, clamp the address and kill the weight for safety.
        if (x1 > 511) { x1 = 511; wx1 = 0.0f; }
        if (y1 > 511) { y1 = 511; wy1 = 0.0f; }
        x0 = max(0, min(511, x0));
        y0 = max(0, min(511, y0));

        const float* bp = tp + ((size_t)p << 23) + q;   // p*R*R*C + q
        const f32x4 v00 = *(const f32x4*)(bp + (((y0 << 9) + x0) << 5));
        const f32x4 v01 = *(const f32x4*)(bp + (((y0 << 9) + x1) << 5));
        const f32x4 v10 = *(const f32x4*)(bp + (((y1 << 9) + x0) << 5));
        const f32x4 v11 = *(const f32x4*)(bp + (((y1 << 9) + x1) << 5));

        const float w00 = wy0 * wx0, w01 = wy0 * wx1;
        const float w10 = wy1 * wx0, w11 = wy1 * wx1;

        acc += w00 * v00 + w01 * v01 + w10 * v10 + w11 * v11;
    }

    __builtin_nontemporal_store(acc, (f32x4*)(out + ((size_t)m << 5) + q));
}

// ---------------- Fallback: direct sample from [3][C][R][R] (ws too small) --
__global__ __launch_bounds__(256) void tp_sample_direct(const float* __restrict__ xyz,
                                                        const float* __restrict__ tpl,
                                                        const int* __restrict__ oid,
                                                        float* __restrict__ out,
                                                        int Mtot) {
    const int tid = blockIdx.x * 256 + threadIdx.x;
    const int m = tid >> 5;
    if (m >= Mtot) return;
    const int c = tid & 31;

    const float px = xyz[m * 3 + 0];
    const float py = xyz[m * 3 + 1];
    const float pz = xyz[m * 3 + 2];
    const float gxs[3] = {py, pz, py};
    const float gys[3] = {px, px, pz};
    const float* base = tpl + (size_t)oid[0] * (3u * CTP * RRTP);

    float acc = 0.f;
    #pragma unroll
    for (int p = 0; p < 3; ++p) {
        const float xf = (gxs[p] + 1.0f) * (0.5f * 511.0f);
        const float yf = (gys[p] + 1.0f) * (0.5f * 511.0f);
        const float x0f = floorf(xf), y0f = floorf(yf);
        float wx1 = xf - x0f, wy1 = yf - y0f;
        float wx0 = 1.0f - wx1, wy0 = 1.0f - wy1;
        int x0 = (int)x0f, y0 = (int)y0f;
        int x1 = x0 + 1,   y1 = y0 + 1;
        if (x1 > 511) { x1 = 511; wx1 = 0.0f; }
        if (y1 > 511) { y1 = 511; wy1 = 0.0f; }
        x0 = max(0, min(511, x0));
        y0 = max(0, min(511, y0));
        const float* img = base + ((size_t)p * CTP + c) * RRTP;
        const float v00 = img[(y0 << 9) + x0];
        const float v01 = img[(y0 << 9) + x1];
        const float v10 = img[(y1 << 9) + x0];
        const float v11 = img[(y1 << 9) + x1];
        acc += wy0 * (wx0 * v00 + wx1 * v01) + wy1 * (wx0 * v10 + wx1 * v11);
    }
    out[((size_t)m << 5) + c] = acc;
}

extern "C" void kernel_launch(void* const* d_in, const int* in_sizes, int n_in,
                              void* d_out, int out_size, void* d_ws, size_t ws_size,
                              hipStream_t stream) {
    const float* xyz      = (const float*)d_in[0];
    const float* triplane = (const float*)d_in[1];
    const int*   oid      = (const int*)d_in[2];
    float*       out      = (float*)d_out;
    const int Mtot = in_sizes[0] / 3;          // 1,000,000

    const size_t ws_needed = (size_t)3 * CTP * RRTP * sizeof(float); // 100.7 MB
    if (ws_size >= ws_needed) {
        float* ws = (float*)d_ws;
        tp_transpose<<<3072, 256, 0, stream>>>(triplane, ws, oid);
        const int nthreads = Mtot * 8;
        tp_sample<<<(nthreads + 255) / 256, 256, 0, stream>>>(xyz, ws, out, Mtot);
    } else {
        const int nthreads = Mtot * 32;
        tp_sample_direct<<<(nthreads + 255) / 256, 256, 0, stream>>>(xyz, triplane, oid, out, Mtot);
    }
}

// Round 3
// 202.126 us; speedup vs baseline: 1.3240x; 1.3240x over previous
//
#include <hip/hip_runtime.h>
#include <hip/hip_bf16.h>

// Triplane sampling, MI355X.
// For each point (x,y,z): sample 3 planes at (gx,gy) = (y,x), (z,x), (y,z),
// bilinear, align_corners=True. out[m*32+c] = sum over planes.
//
// Strategy: one-shot repack triplane [3][C][512][512] f32 ->
// channel-last bf16 [3][512][512][C] in d_ws (50.3 MB working set, halves
// gather traffic vs f32), then gather with 4 threads/point, 16B loads.

#define RRTP 262144   // 512*512
#define CTP  32

typedef float        f32x4 __attribute__((ext_vector_type(4)));
typedef unsigned int u32;
typedef u32          u32x4 __attribute__((ext_vector_type(4)));

// ------------- Kernel 1: [3][C][R][R] f32 -> [3][R][R][C] bf16 -------------
__global__ __launch_bounds__(256) void tp_transpose_bf16(const float* __restrict__ in,
                                                         u32* __restrict__ out,
                                                         const int* __restrict__ oid) {
    __shared__ float tile[256][33];            // stride 33: 2-way max both phases
    const int b     = blockIdx.x;              // 0..3071
    const int plane = b >> 10;
    const int rr0   = (b & 1023) << 8;
    const int t     = threadIdx.x;

    const float* src = in + (size_t)oid[0] * (3u * CTP * RRTP)
                          + (size_t)plane * (CTP * RRTP) + rr0 + t;
    #pragma unroll
    for (int c = 0; c < 32; ++c)               // coalesced 256B/wave reads
        tile[t][c] = src[(size_t)c * RRTP];
    __syncthreads();

    // out texel = 32 bf16 = 16 u32. Each thread packs 2 adjacent channels.
    u32* dst = out + (size_t)plane * ((size_t)RRTP * 16) + (size_t)rr0 * 16;
    const int cp = t & 15;                     // u32 index within texel
    #pragma unroll
    for (int k = 0; k < 16; ++k) {
        const int r = (k << 4) + (t >> 4);     // row in tile (0..255)
        const float f0 = tile[r][cp * 2];
        const float f1 = tile[r][cp * 2 + 1];
        const u32 lo = (u32)__bfloat16_as_ushort(__float2bfloat16(f0));
        const u32 hi = (u32)__bfloat16_as_ushort(__float2bfloat16(f1));
        dst[(size_t)r * 16 + cp] = (hi << 16) | lo;   // 1KB/block coalesced
    }
}

// ------------- Kernel 2: gather from channel-last bf16 ---------------------
// 4 threads per point; thread handles 8 channels (4 u32 = 16B per corner).
__global__ __launch_bounds__(256) void tp_sample_bf16(const float* __restrict__ xyz,
                                                      const u32* __restrict__ tp,
                                                      float* __restrict__ out,
                                                      int Mtot) {
    const int tid = blockIdx.x * 256 + threadIdx.x;
    const int m = tid >> 2;
    if (m >= Mtot) return;
    const int qu = (tid & 3) << 2;             // u32 offset within texel

    const float px = xyz[m * 3 + 0];
    const float py = xyz[m * 3 + 1];
    const float pz = xyz[m * 3 + 2];

    const float gxs[3] = {py, pz, py};
    const float gys[3] = {px, px, pz};

    f32x4 alo = {0.f, 0.f, 0.f, 0.f};
    f32x4 ahi = {0.f, 0.f, 0.f, 0.f};

    #pragma unroll
    for (int p = 0; p < 3; ++p) {
        const float xf = (gxs[p] + 1.0f) * (0.5f * 511.0f);
        const float yf = (gys[p] + 1.0f) * (0.5f * 511.0f);
        const float x0f = floorf(xf), y0f = floorf(yf);
        float wx1 = xf - x0f, wy1 = yf - y0f;
        float wx0 = 1.0f - wx1, wy0 = 1.0f - wy1;

        int x0 = (int)x0f, y0 = (int)y0f;
        int x1 = x0 + 1,   y1 = y0 + 1;
        if (x1 > 511) { x1 = 511; wx1 = 0.0f; }   // zero-pad edge semantics
        if (y1 > 511) { y1 = 511; wy1 = 0.0f; }
        x0 = max(0, min(511, x0));
        y0 = max(0, min(511, y0));

        const u32* bp = tp + ((size_t)p << 22) + qu;  // p*R*R*16 + qu
        const u32x4 v00 = *(const u32x4*)(bp + (size_t)(((y0 << 9) + x0) << 4));
        const u32x4 v01 = *(const u32x4*)(bp + (size_t)(((y0 << 9) + x1) << 4));
        const u32x4 v10 = *(const u32x4*)(bp + (size_t)(((y1 << 9) + x0) << 4));
        const u32x4 v11 = *(const u32x4*)(bp + (size_t)(((y1 << 9) + x1) << 4));

        const float w00 = wy0 * wx0, w01 = wy0 * wx1;
        const float w10 = wy1 * wx0, w11 = wy1 * wx1;

        #pragma unroll
        for (int i = 0; i < 4; ++i) {
            const float l00 = __uint_as_float(v00[i] << 16), h00 = __uint_as_float(v00[i] & 0xffff0000u);
            const float l01 = __uint_as_float(v01[i] << 16), h01 = __uint_as_float(v01[i] & 0xffff0000u);
            const float l10 = __uint_as_float(v10[i] << 16), h10 = __uint_as_float(v10[i] & 0xffff0000u);
            const float l11 = __uint_as_float(v11[i] << 16), h11 = __uint_as_float(v11[i] & 0xffff0000u);
            alo[i] = fmaf(w00, l00, fmaf(w01, l01, fmaf(w10, l10, fmaf(w11, l11, alo[i]))));
            ahi[i] = fmaf(w00, h00, fmaf(w01, h01, fmaf(w10, h10, fmaf(w11, h11, ahi[i]))));
        }
    }

    // channels 2*qu .. 2*qu+7, interleave lo/hi
    float* ob = out + ((size_t)m << 5) + (qu << 1);
    f32x4 s0 = {alo[0], ahi[0], alo[1], ahi[1]};
    f32x4 s1 = {alo[2], ahi[2], alo[3], ahi[3]};
    __builtin_nontemporal_store(s0, (f32x4*)ob);
    __builtin_nontemporal_store(s1, (f32x4*)(ob + 4));
}

// ------------- Fallback: direct sample from [3][C][R][R] (ws too small) ----
__global__ __launch_bounds__(256) void tp_sample_direct(const float* __restrict__ xyz,
                                                        const float* __restrict__ tpl,
                                                        const int* __restrict__ oid,
                                                        float* __restrict__ out,
                                                        int Mtot) {
    const int tid = blockIdx.x * 256 + threadIdx.x;
    const int m = tid >> 5;
    if (m >= Mtot) return;
    const int c = tid & 31;

    const float px = xyz[m * 3 + 0];
    const float py = xyz[m * 3 + 1];
    const float pz = xyz[m * 3 + 2];
    const float gxs[3] = {py, pz, py};
    const float gys[3] = {px, px, pz};
    const float* base = tpl + (size_t)oid[0] * (3u * CTP * RRTP);

    float acc = 0.f;
    #pragma unroll
    for (int p = 0; p < 3; ++p) {
        const float xf = (gxs[p] + 1.0f) * (0.5f * 511.0f);
        const float yf = (gys[p] + 1.0f) * (0.5f * 511.0f);
        const float x0f = floorf(xf), y0f = floorf(yf);
        float wx1 = xf - x0f, wy1 = yf - y0f;
        float wx0 = 1.0f - wx1, wy0 = 1.0f - wy1;
        int x0 = (int)x0f, y0 = (int)y0f;
        int x1 = x0 + 1,   y1 = y0 + 1;
        if (x1 > 511) { x1 = 511; wx1 = 0.0f; }
        if (y1 > 511) { y1 = 511; wy1 = 0.0f; }
        x0 = max(0, min(511, x0));
        y0 = max(0, min(511, y0));
        const float* img = base + ((size_t)p * CTP + c) * RRTP;
        const float v00 = img[(y0 << 9) + x0];
        const float v01 = img[(y0 << 9) + x1];
        const float v10 = img[(y1 << 9) + x0];
        const float v11 = img[(y1 << 9) + x1];
        acc += wy0 * (wx0 * v00 + wx1 * v01) + wy1 * (wx0 * v10 + wx1 * v11);
    }
    out[((size_t)m << 5) + c] = acc;
}

extern "C" void kernel_launch(void* const* d_in, const int* in_sizes, int n_in,
                              void* d_out, int out_size, void* d_ws, size_t ws_size,
                              hipStream_t stream) {
    const float* xyz      = (const float*)d_in[0];
    const float* triplane = (const float*)d_in[1];
    const int*   oid      = (const int*)d_in[2];
    float*       out      = (float*)d_out;
    const int Mtot = in_sizes[0] / 3;          // 1,000,000

    const size_t ws_needed = (size_t)3 * RRTP * CTP * 2;   // 50.3 MB bf16
    if (ws_size >= ws_needed) {
        u32* ws = (u32*)d_ws;
        tp_transpose_bf16<<<3072, 256, 0, stream>>>(triplane, ws, oid);
        const int nthreads = Mtot * 4;
        tp_sample_bf16<<<(nthreads + 255) / 256, 256, 0, stream>>>(xyz, ws, out, Mtot);
    } else {
        const int nthreads = Mtot * 32;
        tp_sample_direct<<<(nthreads + 255) / 256, 256, 0, stream>>>(xyz, triplane, oid, out, Mtot);
    }
}